// Round 8
// baseline (1020.508 us; speedup 1.0000x reference)
//
#include <hip/hip_runtime.h>
#include <math.h>

#define D 512
#define HEADS 8
#define NLAYER 6
#define LSEQ 1024
#define BATCH 4
#define DKH 64
#define MTOK (BATCH*LSEQ)   // 4096 tokens
#define EPS 1e-5f
#define EMB_SCALE 22.627416997969522f  // sqrt(512)
#define INV_SCALE 0.125f               // 1/sqrt(64)

typedef __attribute__((ext_vector_type(8))) __bf16 bf16x8;
typedef __attribute__((ext_vector_type(4))) float f32x4;

__device__ __forceinline__ unsigned short f2bf(float x) {
    union { float f; unsigned u; } v; v.f = x;
    unsigned r = (v.u + 0x7FFFu + ((v.u >> 16) & 1u)) >> 16;
    return (unsigned short)r;
}
__device__ __forceinline__ unsigned pack2(float a, float b) {
    return (unsigned)f2bf(a) | ((unsigned)f2bf(b) << 16);
}
__device__ __forceinline__ void gl_lds16(const unsigned short* g, unsigned short* l) {
    __builtin_amdgcn_global_load_lds(
        (const __attribute__((address_space(1))) unsigned*)g,
        (__attribute__((address_space(3))) unsigned*)l, 16, 0, 0);
}
// asm 16B global load (attn): volatile asm cannot be sunk -> pipeline holds.
__device__ __forceinline__ void gload16(bf16x8& d, const unsigned short* p) {
    asm volatile("global_load_dwordx4 %0, %1, off" : "=v"(d) : "v"(p));
}

// ---------------- prep: weights fp32->bf16, biases, stats-zero, embed+stats ----
// R8: LN is now fused into the GEMMs. prep additionally (a) zeroes the 12
// atomically-accumulated row-stat buffers, (b) computes layer-0 ln1 stats
// directly from the embedding output (1 wave per row).
__global__ __launch_bounds__(256) void prep_kernel(
    const int* __restrict__ tokens, const float* __restrict__ emb,
    const float* __restrict__ Wq, const float* __restrict__ Wkv,
    const float* __restrict__ Wo, const float* __restrict__ W1,
    const float* __restrict__ W2, const float* __restrict__ bq,
    const float* __restrict__ bkv, unsigned short* __restrict__ wl,
    float* __restrict__ wbias, float* __restrict__ stats,
    float* __restrict__ x)
{
    const int bid = blockIdx.x;
    if (bid < 9216) {                       // weight conversion, 6 layers
        const int l = bid / 1536;
        const int e = (bid - l * 1536) * 2048 + threadIdx.x * 8;
        const float* src;
        if      (e < 262144)  src = Wq  + (size_t)l * 262144  + e;
        else if (e < 786432)  src = Wkv + (size_t)l * 524288  + (e - 262144);
        else if (e < 1048576) src = Wo  + (size_t)l * 262144  + (e - 786432);
        else if (e < 2097152) src = W1  + (size_t)l * 1048576 + (e - 1048576);
        else                  src = W2  + (size_t)l * 1048576 + (e - 2097152);
        float4 a = *(const float4*)src;
        float4 b = *(const float4*)(src + 4);
        uint4 o;
        o.x = pack2(a.x, a.y); o.y = pack2(a.z, a.w);
        o.z = pack2(b.x, b.y); o.w = pack2(b.z, b.w);
        *(uint4*)(wl + (size_t)l * 3145728 + e) = o;
    } else if (bid == 9216) {               // combined QKV biases, 6 layers
        for (int i = threadIdx.x; i < 9216; i += 256) {
            int l = i / 1536, j = i - l * 1536;
            wbias[i] = (j < 512) ? bq[l * 512 + j] : bkv[l * 1024 + (j - 512)];
        }
    } else if (bid < 9313) {                // zero stats[8192..106496)
        int i = (bid - 9217) * 1024 + threadIdx.x * 4;
        *(float4*)&stats[8192 + i] = (float4){0.f, 0.f, 0.f, 0.f};
    } else {                                // embedding + PE + ln1[0] stats
        int row = (bid - 9313) * 4 + (threadIdx.x >> 6);
        int lane = threadIdx.x & 63;
        int pos = row & (LSEQ - 1);
        int tok = tokens[row];
        int c = lane * 8;
        const float* ep = emb + (size_t)tok * D + c;
        float4 e0 = *(const float4*)ep;
        float4 e1 = *(const float4*)(ep + 4);
        float v[8] = {e0.x, e0.y, e0.z, e0.w, e1.x, e1.y, e1.z, e1.w};
        float s = 0.f, ss = 0.f;
#pragma unroll
        for (int i = 0; i < 8; ++i) {
            int col = c + i, ii = col & ~1;
            float dv = expf(-(float)ii * (9.210340371976184f / (float)D));
            float a = (float)pos * dv;
            float pe = (col & 1) ? cosf(a) : sinf(a);
            v[i] = v[i] * EMB_SCALE + pe;
            s += v[i]; ss += v[i] * v[i];
        }
        float4 r0; r0.x = v[0]; r0.y = v[1]; r0.z = v[2]; r0.w = v[3];
        float4 r1; r1.x = v[4]; r1.y = v[5]; r1.z = v[6]; r1.w = v[7];
        *(float4*)(x + (size_t)row * D + c) = r0;
        *(float4*)(x + (size_t)row * D + c + 4) = r1;
#pragma unroll
        for (int off = 1; off < 64; off <<= 1) {
            s  += __shfl_xor(s,  off, 64);
            ss += __shfl_xor(ss, off, 64);
        }
        if (lane == 0) { stats[row * 2] = s; stats[row * 2 + 1] = ss; }
    }
}

// ---------------- bf16 MFMA GEMM: acc = A(bf16 MxK) @ W(bf16 NxK)^T ----------------
// 2-phase double-buffered pipeline, BK=64, XOR-swizzled LDS (R3/R4 validated).
// R8 additions:
//  LNA=1: A is fp32 x with LayerNorm applied on the fly during staging.
//    T14 split: XLOAD(t+1) issues x/gamma/beta loads BEFORE COMPUTE(t); after
//    COMPUTE, XWRITE applies (x-mean)*inv*g+b, packs bf16, ds_write_b128 into
//    the SAME swizzled LDS slot gl_lds would have filled. Row stats come from
//    lstats[m]={sum,sumsq} (written by the previous GEMM's epilogue).
//  OMODE 0: epilogue additionally shuffle-reduces row partials and atomicAdds
//    {sum,sumsq} into statsOut for the NEXT LN consumer (device-scope; the
//    consumer is a later dispatch, so ordering is guaranteed).
template<int OMODE, int BM, int LNA>
__global__ __launch_bounds__(256) void gemm_bf16(
    const unsigned short* __restrict__ A,
    const float* __restrict__ Ax, const float* __restrict__ lstats,
    const float* __restrict__ lg, const float* __restrict__ lb,
    const unsigned short* __restrict__ W,
    const float* __restrict__ bias, const float* __restrict__ X,
    void* __restrict__ C, void* __restrict__ C2, void* __restrict__ C3,
    float* __restrict__ statsOut,
    int M, int N, int K)
{
    constexpr int WM = BM / 64;       // 2 or 1
    constexpr int WN = 4 / WM;        // 2 or 4
    constexpr int NI = 8 / WN;        // 4 or 2 (16-col frags per wave)
    constexpr int LPTA = BM / 32;     // A row-groups per staging thread
    __shared__ __align__(16) unsigned short As[2][BM * 64];
    __shared__ __align__(16) unsigned short Bs[2][128 * 64];
    const int tid = threadIdx.x;
    const int wave = tid >> 6, lane = tid & 63;
    const int quad = lane >> 4, l16 = lane & 15;
    const int wm = wave / WN, wn = wave % WN;
    const int bm = blockIdx.y * BM, bn = blockIdx.x * 128;

    // staging: thread t covers row (t>>3) of each 32-row group, 8 elems.
    // source column chunk is XOR-swizzled so linear LDS holds swizzled data.
    const int rS  = tid >> 3;
    const int csw = (((tid & 7) ^ (rS & 7)) << 3);
    const unsigned short* Bsrc = W + (size_t)(bn + rS) * K + csw;

    f32x4 acc[4][NI];
#pragma unroll
    for (int mi = 0; mi < 4; ++mi)
#pragma unroll
        for (int ni = 0; ni < NI; ++ni) acc[mi][ni] = (f32x4){0.f, 0.f, 0.f, 0.f};

    const int nt = K >> 6;

    auto COMPUTE = [&](int cur) {
#pragma unroll
        for (int kc = 0; kc < 2; ++kc) {
            const int gch = (kc << 2) | quad;   // global col chunk this quad wants
            bf16x8 af[4], bfr[NI];
#pragma unroll
            for (int mi = 0; mi < 4; ++mi) {
                const int ra = wm * 64 + mi * 16 + l16;
                af[mi] = *(const bf16x8*)&As[cur][ra * 64 + ((gch ^ (ra & 7)) << 3)];
            }
#pragma unroll
            for (int ni = 0; ni < NI; ++ni) {
                const int rb = wn * (128 / WN) + ni * 16 + l16;
                bfr[ni] = *(const bf16x8*)&Bs[cur][rb * 64 + ((gch ^ (rb & 7)) << 3)];
            }
#pragma unroll
            for (int mi = 0; mi < 4; ++mi)
#pragma unroll
                for (int ni = 0; ni < NI; ++ni)
                    acc[mi][ni] = __builtin_amdgcn_mfma_f32_16x16x32_bf16(
                        af[mi], bfr[ni], acc[mi][ni], 0, 0, 0);
        }
    };
    auto BSTAGE = [&](int t, int buf) {
        const int k0 = t << 6;
#pragma unroll
        for (int i = 0; i < 4; ++i)
            gl_lds16(Bsrc + (size_t)(i * 32) * K + k0, &Bs[buf][i * 2048 + tid * 8]);
    };

    if constexpr (LNA) {
        // ---- fused-LN A staging (fp32 x -> bf16 LDS) ----
        float meanv[LPTA], invv[LPTA];
#pragma unroll
        for (int i = 0; i < LPTA; ++i) {
            float sm = lstats[(size_t)(bm + rS + i * 32) * 2];
            float sq = lstats[(size_t)(bm + rS + i * 32) * 2 + 1];
            float mm = sm * (1.0f / D);
            meanv[i] = mm;
            invv[i]  = rsqrtf(sq * (1.0f / D) - mm * mm + EPS);
        }
        float4 xv[LPTA][2], gv[2], bvv[2];
        auto XLOAD = [&](int t) {
            const int col = csw + (t << 6);
            gv[0]  = *(const float4*)(lg + col);
            gv[1]  = *(const float4*)(lg + col + 4);
            bvv[0] = *(const float4*)(lb + col);
            bvv[1] = *(const float4*)(lb + col + 4);
#pragma unroll
            for (int i = 0; i < LPTA; ++i) {
                const float* xr = Ax + (size_t)(bm + rS + i * 32) * K + col;
                xv[i][0] = *(const float4*)xr;
                xv[i][1] = *(const float4*)(xr + 4);
            }
        };
        auto XWRITE = [&](int buf) {
#pragma unroll
            for (int i = 0; i < LPTA; ++i) {
                float mm = meanv[i], iv = invv[i];
                uint4 o;
                o.x = pack2((xv[i][0].x - mm) * iv * gv[0].x + bvv[0].x,
                            (xv[i][0].y - mm) * iv * gv[0].y + bvv[0].y);
                o.y = pack2((xv[i][0].z - mm) * iv * gv[0].z + bvv[0].z,
                            (xv[i][0].w - mm) * iv * gv[0].w + bvv[0].w);
                o.z = pack2((xv[i][1].x - mm) * iv * gv[1].x + bvv[1].x,
                            (xv[i][1].y - mm) * iv * gv[1].y + bvv[1].y);
                o.w = pack2((xv[i][1].z - mm) * iv * gv[1].z + bvv[1].z,
                            (xv[i][1].w - mm) * iv * gv[1].w + bvv[1].w);
                *(uint4*)&As[buf][i * 2048 + tid * 8] = o;
            }
        };
        XLOAD(0);
        BSTAGE(0, 0);
        XWRITE(0);
        __syncthreads();
        for (int t = 0; t < nt; ++t) {
            const int cur = t & 1;
            if (t + 1 < nt) { XLOAD(t + 1); BSTAGE(t + 1, cur ^ 1); }
            COMPUTE(cur);
            if (t + 1 < nt) XWRITE(cur ^ 1);
            __syncthreads();
        }
    } else {
        const unsigned short* Asrc = A + (size_t)(bm + rS) * K + csw;
#pragma unroll
        for (int i = 0; i < LPTA; ++i)
            gl_lds16(Asrc + (size_t)(i * 32) * K, &As[0][i * 2048 + tid * 8]);
        BSTAGE(0, 0);
        __syncthreads();
        for (int t = 0; t < nt; ++t) {
            const int cur = t & 1;
            if (t + 1 < nt) {
                const int k0 = (t + 1) << 6;
#pragma unroll
                for (int i = 0; i < LPTA; ++i)
                    gl_lds16(Asrc + (size_t)(i * 32) * K + k0, &As[cur ^ 1][i * 2048 + tid * 8]);
                BSTAGE(t + 1, cur ^ 1);
            }
            COMPUTE(cur);
            __syncthreads();
        }
    }

    const int er = bm + wm * 64;
    const int ec = bn + wn * (128 / WN);

    if (OMODE == 0) {
        float* Cf = (float*)C;
#pragma unroll
        for (int mi = 0; mi < 4; ++mi)
#pragma unroll
            for (int r = 0; r < 4; ++r) {
                int m = er + mi * 16 + quad * 4 + r;
                float s = 0.f, sq = 0.f;
#pragma unroll
                for (int ni = 0; ni < NI; ++ni) {
                    int c = ec + ni * 16 + l16;
                    float val = acc[mi][ni][r] + bias[c] + X[(size_t)m * N + c];
                    Cf[(size_t)m * N + c] = val;
                    s += val; sq += val * val;
                }
#pragma unroll
                for (int off = 1; off < 16; off <<= 1) {
                    s  += __shfl_xor(s,  off, 64);
                    sq += __shfl_xor(sq, off, 64);
                }
                if (l16 == 0) {
                    atomicAdd(&statsOut[(size_t)m * 2],     s);
                    atomicAdd(&statsOut[(size_t)m * 2 + 1], sq);
                }
            }
    } else if (OMODE == 1) {
        unsigned short* Cb = (unsigned short*)C;
#pragma unroll
        for (int ni = 0; ni < NI; ++ni) {
            int c = ec + ni * 16 + l16;
            float bv = bias[c];
#pragma unroll
            for (int mi = 0; mi < 4; ++mi)
#pragma unroll
                for (int r = 0; r < 4; ++r) {
                    int m = er + mi * 16 + quad * 4 + r;
                    Cb[(size_t)m * N + c] = f2bf(fmaxf(acc[mi][ni][r] + bv, 0.f));
                }
        }
    } else {
        if (bn < 512) {            // Q (scaled), fragment-linear
            unsigned short* Qp = (unsigned short*)C;
#pragma unroll
            for (int ni = 0; ni < NI; ++ni) {
                int c = ec + ni * 16 + l16;
                float bv = bias[c];
                int hh = c >> 6, dd = c & 63;
                size_t cbase = (size_t)(dd >> 5) * 512 + (size_t)((dd >> 3) & 3) * 128 + (dd & 7);
#pragma unroll
                for (int mi = 0; mi < 4; ++mi)
#pragma unroll
                    for (int r = 0; r < 4; ++r) {
                        int m = er + mi * 16 + quad * 4 + r;
                        int b = m >> 10, t = m & 1023;
                        Qp[(size_t)(b * 8 + hh) * 65536 + (size_t)(t >> 4) * 1024
                           + cbase + (size_t)(t & 15) * 8] =
                            f2bf((acc[mi][ni][r] + bv) * INV_SCALE);
                    }
            }
        } else if (bn < 1024) {    // K, fragment-linear
            unsigned short* Kp = (unsigned short*)C2;
#pragma unroll
            for (int ni = 0; ni < NI; ++ni) {
                int c = ec + ni * 16 + l16;
                float bv = bias[c];
                int c2 = c - 512;
                int hh = c2 >> 6, dd = c2 & 63;
                size_t cbase = (size_t)(dd >> 5) * 512 + (size_t)((dd >> 3) & 3) * 128 + (dd & 7);
#pragma unroll
                for (int mi = 0; mi < 4; ++mi)
#pragma unroll
                    for (int r = 0; r < 4; ++r) {
                        int m = er + mi * 16 + quad * 4 + r;
                        int b = m >> 10, t = m & 1023;
                        Kp[(size_t)(b * 8 + hh) * 65536 + (size_t)(t >> 4) * 1024
                           + cbase + (size_t)(t & 15) * 8] =
                            f2bf(acc[mi][ni][r] + bv);
                    }
            }
        } else {                   // V, fragment-linear (transposed consumption)
            unsigned short* Vp = (unsigned short*)C3;
#pragma unroll
            for (int ni = 0; ni < NI; ++ni) {
                int c = ec + ni * 16 + l16;
                float bv = bias[c];
                int c2 = c - 1024;
                int hh = c2 >> 6, dd = c2 & 63;
                size_t dbase = (size_t)(dd >> 4) * 16384 + (size_t)(dd & 15) * 8;
#pragma unroll
                for (int mi = 0; mi < 4; ++mi) {
                    int t0 = er + mi * 16 + quad * 4;
                    int b = t0 >> 10, tt = t0 & 1023;
                    ushort4 o;
                    o.x = f2bf(acc[mi][ni][0] + bv);
                    o.y = f2bf(acc[mi][ni][1] + bv);
                    o.z = f2bf(acc[mi][ni][2] + bv);
                    o.w = f2bf(acc[mi][ni][3] + bv);
                    *(ushort4*)(Vp + (size_t)(b * 8 + hh) * 65536 + dbase
                                + (size_t)(tt >> 5) * 512
                                + (size_t)((tt >> 3) & 3) * 128 + (tt & 7)) = o;
                }
            }
        }
    }
}

// ---------------- flash attention: split-K, QROWS=32 per block (R4 best) ----
// Fragment-linear layouts + asm-pinned double-buffered private loads.
__global__ __launch_bounds__(256, 1) void attn_mfma(
    const unsigned short* __restrict__ Qb, const unsigned short* __restrict__ Kb,
    const unsigned short* __restrict__ Vt, unsigned short* __restrict__ av)
{
    __shared__ float Ol[4][32][68];   // [wave][q][d] fp32 partial O (+pad)
    __shared__ float Ls[4][32];       // [wave][q] partial denominators
    const int tid = threadIdx.x;
    const int wave = tid >> 6, lane = tid & 63;
    const int quad = lane >> 4, l16 = lane & 15;
    const int bh = blockIdx.x & 31;          // xcd = bh % 8 -> K/V L2-resident per XCD
    const int b = bh >> 3, h = bh & 7;
    const int q0 = (blockIdx.x >> 5) * 32;   // 32 q-tiles of 32 rows

    const unsigned short* qp = Qb + (size_t)bh * 65536 + (size_t)(q0 >> 4) * 1024 + lane * 8;
    const unsigned short* kbase = Kb + (size_t)bh * 65536 + lane * 8;
    const unsigned short* vbase = Vt + (size_t)bh * 65536 + lane * 8;

    // bpermute byte addresses: pull from quad (2q)&3 / (2q+1)&3 at same l16
    const int sA  = ((((2 * quad) & 3) << 4) + l16) << 2;
    const int sB2 = ((((2 * quad + 1) & 3) << 4) + l16) << 2;

    f32x4 o[2][4];
#pragma unroll
    for (int qs = 0; qs < 2; ++qs)
#pragma unroll
        for (int nf = 0; nf < 4; ++nf) o[qs][nf] = (f32x4){0.f, 0.f, 0.f, 0.f};
    float lp[2] = {0.f, 0.f};   // per-lane partial column (=query) sums

    const int j0 = wave * 256;

    // ---- prologue: issue Q (4) + buffer0 K/V (16) loads; 20 in flight ----
    bf16x8 qf[2][2];
    gload16(qf[0][0], qp);
    gload16(qf[0][1], qp + 512);
    gload16(qf[1][0], qp + 1024);
    gload16(qf[1][1], qp + 1536);

    bf16x8 kc[2][8], vf[2][8];
#pragma unroll
    for (int nf = 0; nf < 4; ++nf) {
        gload16(kc[0][2 * nf],     kbase + (size_t)j0 * 64 + nf * 1024);
        gload16(kc[0][2 * nf + 1], kbase + (size_t)j0 * 64 + nf * 1024 + 512);
        gload16(vf[0][2 * nf],     vbase + (size_t)j0 * 16 + nf * 16384);
        gload16(vf[0][2 * nf + 1], vbase + (size_t)j0 * 16 + nf * 16384 + 512);
    }

#pragma unroll
    for (int it = 0; it < 4; ++it) {
        const int cur = it & 1, nxt = cur ^ 1;
        // ---- issue next tile's 16 loads BEFORE waiting on current ----
        if (it < 3) {
            const int jn = j0 + (it + 1) * 64;
#pragma unroll
            for (int nf = 0; nf < 4; ++nf) {
                gload16(kc[nxt][2 * nf],     kbase + (size_t)jn * 64 + nf * 1024);
                gload16(kc[nxt][2 * nf + 1], kbase + (size_t)jn * 64 + nf * 1024 + 512);
                gload16(vf[nxt][2 * nf],     vbase + (size_t)jn * 16 + nf * 16384);
                gload16(vf[nxt][2 * nf + 1], vbase + (size_t)jn * 16 + nf * 16384 + 512);
            }
        }
        // ---- counted wait: current buffer (+Q at it=0) done, next 16 in flight ----
        if (it < 3) asm volatile("s_waitcnt vmcnt(16)" ::: "memory");
        else        asm volatile("s_waitcnt vmcnt(0)"  ::: "memory");
        __builtin_amdgcn_sched_barrier(0);
        // ---- S^T tiles (row=key, col=query), exp, pack — per (nf, qs) ----
        unsigned pk01[2][4], pk23[2][4];
#pragma unroll
        for (int nf = 0; nf < 4; ++nf)
#pragma unroll
            for (int qs = 0; qs < 2; ++qs) {
                f32x4 z = {0.f, 0.f, 0.f, 0.f};
                z = __builtin_amdgcn_mfma_f32_16x16x32_bf16(kc[cur][2 * nf], qf[qs][0], z, 0, 0, 0);
                z = __builtin_amdgcn_mfma_f32_16x16x32_bf16(kc[cur][2 * nf + 1], qf[qs][1], z, 0, 0, 0);
                float p0 = __expf(z[0]);
                float p1 = __expf(z[1]);
                float p2 = __expf(z[2]);
                float p3 = __expf(z[3]);
                lp[qs] += (p0 + p1) + (p2 + p3);
                pk01[qs][nf] = pack2(p0, p1);
                pk23[qs][nf] = pack2(p2, p3);
            }
        // ---- register-only C->A transform (validated), per q-subtile ----
#pragma unroll
        for (int qs = 0; qs < 2; ++qs) {
            union PU { unsigned d[4]; bf16x8 v; } f0, f1;
            unsigned a0, a1;
            a0 = (unsigned)__builtin_amdgcn_ds_bpermute(sA,  (int)pk01[qs][0]);
            a1 = (unsigned)__builtin_amdgcn_ds_bpermute(sA,  (int)pk01[qs][1]);
            f0.d[0] = (quad < 2) ? a0 : a1;
            a0 = (unsigned)__builtin_amdgcn_ds_bpermute(sA,  (int)pk23[qs][0]);
            a1 = (unsigned)__builtin_amdgcn_ds_bpermute(sA,  (int)pk23[qs][1]);
            f0.d[1] = (quad < 2) ? a0 : a1;
            a0 = (unsigned)__builtin_amdgcn_ds_bpermute(sB2, (int)pk01[qs][0]);
            a1 = (unsigned)__builtin_amdgcn_ds_bpermute(sB2, (int)pk01[qs][1]);
            f0.d[2] = (quad < 2) ? a0 : a1;
            a0 = (unsigned)__builtin_amdgcn_ds_bpermute(sB2, (int)pk23[qs][0]);
            a1 = (unsigned)__builtin_amdgcn_ds_bpermute(sB2, (int)pk23[qs][1]);
            f0.d[3] = (quad < 2) ? a0 : a1;
            a0 = (unsigned)__builtin_amdgcn_ds_bpermute(sA,  (int)pk01[qs][2]);
            a1 = (unsigned)__builtin_amdgcn_ds_bpermute(sA,  (int)pk01[qs][3]);
            f1.d[0] = (quad < 2) ? a0 : a1;
            a0 = (unsigned)__builtin_amdgcn_ds_bpermute(sA,  (int)pk23[qs][2]);
            a1 = (unsigned)__builtin_amdgcn_ds_bpermute(sA,  (int)pk23[qs][3]);
            f1.d[1] = (quad < 2) ? a0 : a1;
            a0 = (unsigned)__builtin_amdgcn_ds_bpermute(sB2, (int)pk01[qs][2]);
            a1 = (unsigned)__builtin_amdgcn_ds_bpermute(sB2, (int)pk01[qs][3]);
            f1.d[2] = (quad < 2) ? a0 : a1;
            a0 = (unsigned)__builtin_amdgcn_ds_bpermute(sB2, (int)pk23[qs][2]);
            a1 = (unsigned)__builtin_amdgcn_ds_bpermute(sB2, (int)pk23[qs][3]);
            f1.d[3] = (quad < 2) ? a0 : a1;
            // ---- O += P.V ----
#pragma unroll
            for (int nf = 0; nf < 4; ++nf) {
                o[qs][nf] = __builtin_amdgcn_mfma_f32_16x16x32_bf16(f0.v, vf[cur][2 * nf], o[qs][nf], 0, 0, 0);
                o[qs][nf] = __builtin_amdgcn_mfma_f32_16x16x32_bf16(f1.v, vf[cur][2 * nf + 1], o[qs][nf], 0, 0, 0);
            }
        }
    }
    // ---- write per-wave partials to LDS ----
#pragma unroll
    for (int qs = 0; qs < 2; ++qs)
#pragma unroll
        for (int nf = 0; nf < 4; ++nf)
#pragma unroll
            for (int r = 0; r < 4; ++r)
                Ol[wave][qs * 16 + quad * 4 + r][nf * 16 + l16] = o[qs][nf][r];
#pragma unroll
    for (int qs = 0; qs < 2; ++qs) {
        float ts = lp[qs];
        ts += __shfl_xor(ts, 16, 64);
        ts += __shfl_xor(ts, 32, 64);
        if (quad == 0) Ls[wave][qs * 16 + l16] = ts;
    }
    __syncthreads();
    // ---- combine: wave w handles d-frag nf=w, 32 q rows ----
#pragma unroll
    for (int half = 0; half < 2; ++half)
#pragma unroll
        for (int r = 0; r < 4; ++r) {
            int qq = half * 16 + quad * 4 + r;
            float denom = Ls[0][qq] + Ls[1][qq] + Ls[2][qq] + Ls[3][qq];
            float v = Ol[0][qq][wave * 16 + l16] + Ol[1][qq][wave * 16 + l16]
                    + Ol[2][qq][wave * 16 + l16] + Ol[3][qq][wave * 16 + l16];
            int q = q0 + qq;
            av[((size_t)(b * 1024 + q)) * D + h * 64 + wave * 16 + l16] =
                f2bf(v / denom);
        }
}

// ---------------- classifier ----------------
__global__ __launch_bounds__(256) void cls_kernel(
    const float* __restrict__ x, const float* __restrict__ Wc,
    const float* __restrict__ bc, float* __restrict__ out)
{
    int lane = threadIdx.x & 63;
    int row = blockIdx.x * 4 + (threadIdx.x >> 6);
    const float* xr = x + (size_t)row * D + lane * 8;
    float4 v0 = *(const float4*)xr;
    float4 v1 = *(const float4*)(xr + 4);
    float acc[10];
#pragma unroll
    for (int c = 0; c < 10; ++c) {
        const float* wr = Wc + c * D + lane * 8;
        float4 w0 = *(const float4*)wr;
        float4 w1 = *(const float4*)(wr + 4);
        acc[c] = v0.x*w0.x + v0.y*w0.y + v0.z*w0.z + v0.w*w0.w
               + v1.x*w1.x + v1.y*w1.y + v1.z*w1.z + v1.w*w1.w;
    }
#pragma unroll
    for (int c = 0; c < 10; ++c)
#pragma unroll
        for (int off = 32; off; off >>= 1) acc[c] += __shfl_xor(acc[c], off, 64);
    if (lane == 0) {
#pragma unroll
        for (int c = 0; c < 10; ++c) out[(size_t)row * 10 + c] = acc[c] + bc[c];
    }
}

extern "C" void kernel_launch(void* const* d_in, const int* in_sizes, int n_in,
                              void* d_out, int out_size, void* d_ws, size_t ws_size,
                              hipStream_t stream)
{
    const int*   tokens = (const int*)  d_in[0];
    const float* emb    = (const float*)d_in[1];
    const float* Wq     = (const float*)d_in[2];
    const float* bq     = (const float*)d_in[3];
    const float* Wkv    = (const float*)d_in[4];
    const float* bkv    = (const float*)d_in[5];
    const float* Wo     = (const float*)d_in[6];
    const float* bo     = (const float*)d_in[7];
    const float* ln1g   = (const float*)d_in[8];
    const float* ln1b   = (const float*)d_in[9];
    const float* W1     = (const float*)d_in[10];
    const float* b1     = (const float*)d_in[11];
    const float* W2     = (const float*)d_in[12];
    const float* b2     = (const float*)d_in[13];
    const float* ln2g   = (const float*)d_in[14];
    const float* ln2b   = (const float*)d_in[15];
    const float* Wc     = (const float*)d_in[16];
    const float* bc     = (const float*)d_in[17];
    float* out = (float*)d_out;

    // workspace (~65 MB; harness poisons >=268MB per fillBuffer WRITE_SIZE):
    // x fp32 8MB | (hb slot 4MB, unused) | Qb 4 | Kb 4 | Vt 4 | avb 4
    // (f1b aliases Qb..) | wl bf16 36MB | wbias 36KB | stats 416KB
    float* x  = (float*)d_ws;
    unsigned short* hb  = (unsigned short*)(x + (size_t)MTOK * D);
    unsigned short* Qb  = hb  + (size_t)MTOK * D;
    unsigned short* Kb  = Qb  + (size_t)32 * 1024 * 64;
    unsigned short* Vt  = Kb  + (size_t)32 * 1024 * 64;
    unsigned short* avb = Vt  + (size_t)32 * 1024 * 64;
    unsigned short* f1b = Qb;                              // [4096][2048] bf16 = 16 MB
    unsigned short* wl  = avb + (size_t)32 * 1024 * 64;    // all-layer bf16 weights (36 MB)
    float* wbias = (float*)(wl + (size_t)6 * 3145728);     // combined [bq;bkv] x 6 (36 KB)
    float* stats = wbias + 9216;                           // 13 x [4096][2] row stats
    // stats layout: ln1 stats for layer l at stats + l*8192 (l=0..6; l=0 by
    // prep, l>=1 by FFN2 of layer l-1); ln2 stats at stats + (7+l)*8192.

    const size_t oWo = 786432, oW1 = 1048576, oW2 = 2097152, LW = 3145728;

    prep_kernel<<<10337, 256, 0, stream>>>(
        tokens, emb, Wq, Wkv, Wo, W1, W2, bq, bkv, wl, wbias, stats, x);

    for (int l = 0; l < NLAYER; ++l) {
        const unsigned short* wll = wl + (size_t)l * LW;
        float* s_ln1  = stats + (size_t)l * 8192;
        float* s_ln1n = stats + (size_t)(l + 1) * 8192;
        float* s_ln2  = stats + (size_t)(7 + l) * 8192;
        // QKV GEMM with fused ln1 (A = x fp32, normalized on the fly)
        gemm_bf16<2, 128, 1><<<dim3(12, 32), 256, 0, stream>>>(
            nullptr, x, s_ln1, ln1g + l * D, ln1b + l * D,
            wll, wbias + l * 1536, nullptr, Qb, Kb, Vt, nullptr, MTOK, 1536, 512);
        attn_mfma<<<1024, 256, 0, stream>>>(Qb, Kb, Vt, avb);
        // Wo GEMM: x += av@Wo^T + bo; epilogue accumulates ln2 stats
        gemm_bf16<0, 64, 0><<<dim3(4, 64), 256, 0, stream>>>(
            avb, nullptr, nullptr, nullptr, nullptr,
            wll + oWo, bo + l * D, x, x, nullptr, nullptr, s_ln2, MTOK, D, D);
        // FFN1 GEMM with fused ln2
        gemm_bf16<1, 128, 1><<<dim3(16, 32), 256, 0, stream>>>(
            nullptr, x, s_ln2, ln2g + l * D, ln2b + l * D,
            wll + oW1, b1 + l * 4 * D, nullptr, f1b, nullptr, nullptr, nullptr,
            MTOK, 4 * D, D);
        // FFN2 GEMM: x += f1b@W2^T + b2; epilogue accumulates next ln1 stats
        gemm_bf16<0, 64, 0><<<dim3(4, 64), 256, 0, stream>>>(
            f1b, nullptr, nullptr, nullptr, nullptr,
            wll + oW2, b2 + l * D, x, x, nullptr, nullptr, s_ln1n, MTOK, D, 4 * D);
    }

    cls_kernel<<<MTOK / 4, 256, 0, stream>>>(x, Wc, bc, out);
}

// Round 9
// 715.169 us; speedup vs baseline: 1.4269x; 1.4269x over previous
//
#include <hip/hip_runtime.h>
#include <math.h>

#define D 512
#define HEADS 8
#define NLAYER 6
#define LSEQ 1024
#define BATCH 4
#define DKH 64
#define MTOK (BATCH*LSEQ)   // 4096 tokens
#define EPS 1e-5f
#define EMB_SCALE 22.627416997969522f  // sqrt(512)
#define INV_SCALE 0.125f               // 1/sqrt(64)

typedef __attribute__((ext_vector_type(8))) __bf16 bf16x8;
typedef __attribute__((ext_vector_type(4))) float f32x4;

__device__ __forceinline__ unsigned short f2bf(float x) {
    union { float f; unsigned u; } v; v.f = x;
    unsigned r = (v.u + 0x7FFFu + ((v.u >> 16) & 1u)) >> 16;
    return (unsigned short)r;
}
__device__ __forceinline__ unsigned pack2(float a, float b) {
    return (unsigned)f2bf(a) | ((unsigned)f2bf(b) << 16);
}
__device__ __forceinline__ void gl_lds16(const unsigned short* g, unsigned short* l) {
    __builtin_amdgcn_global_load_lds(
        (const __attribute__((address_space(1))) unsigned*)g,
        (__attribute__((address_space(3))) unsigned*)l, 16, 0, 0);
}
// asm 16B global load (attn): volatile asm cannot be sunk -> pipeline holds.
__device__ __forceinline__ void gload16(bf16x8& d, const unsigned short* p) {
    asm volatile("global_load_dwordx4 %0, %1, off" : "=v"(d) : "v"(p));
}

// ---------------- prep: ALL-layer weight fp32->bf16 + biases + embedding ----
// R7-validated (789us). R8's LN-fusion regressed (1020us) -> fully reverted:
// fused staging lost global_load_lds + tripled A traffic + stat-epilogue cost
// exceeded the 12 saved dispatch boundaries.
__global__ __launch_bounds__(256) void prep_kernel(
    const int* __restrict__ tokens, const float* __restrict__ emb,
    const float* __restrict__ Wq, const float* __restrict__ Wkv,
    const float* __restrict__ Wo, const float* __restrict__ W1,
    const float* __restrict__ W2, const float* __restrict__ bq,
    const float* __restrict__ bkv, unsigned short* __restrict__ wl,
    float* __restrict__ wbias, float* __restrict__ x)
{
    const int bid = blockIdx.x;
    if (bid < 9216) {                       // weight conversion, 6 layers
        const int l = bid / 1536;
        const int e = (bid - l * 1536) * 2048 + threadIdx.x * 8;
        const float* src;
        if      (e < 262144)  src = Wq  + (size_t)l * 262144  + e;
        else if (e < 786432)  src = Wkv + (size_t)l * 524288  + (e - 262144);
        else if (e < 1048576) src = Wo  + (size_t)l * 262144  + (e - 786432);
        else if (e < 2097152) src = W1  + (size_t)l * 1048576 + (e - 1048576);
        else                  src = W2  + (size_t)l * 1048576 + (e - 2097152);
        float4 a = *(const float4*)src;
        float4 b = *(const float4*)(src + 4);
        uint4 o;
        o.x = pack2(a.x, a.y); o.y = pack2(a.z, a.w);
        o.z = pack2(b.x, b.y); o.w = pack2(b.z, b.w);
        *(uint4*)(wl + (size_t)l * 3145728 + e) = o;
    } else if (bid == 9216) {               // combined QKV biases, 6 layers
        for (int i = threadIdx.x; i < 9216; i += 256) {
            int l = i / 1536, j = i - l * 1536;
            wbias[i] = (j < 512) ? bq[l * 512 + j] : bkv[l * 1024 + (j - 512)];
        }
    } else {                                // embedding + positional encoding
        int row = (bid - 9217) * 2 + (threadIdx.x >> 7);
        int pos = row & (LSEQ - 1);
        int tok = tokens[row];
        int c = (threadIdx.x & 127) * 4;
        float4 e = *(const float4*)(emb + (size_t)tok * D + c);
        float o[4] = {e.x, e.y, e.z, e.w};
#pragma unroll
        for (int i = 0; i < 4; ++i) {
            int col = c + i;
            int ii = col & ~1;
            float dv = expf(-(float)ii * (9.210340371976184f / (float)D));
            float a = (float)pos * dv;
            float pe = (col & 1) ? cosf(a) : sinf(a);
            o[i] = o[i] * EMB_SCALE + pe;
        }
        float4 r; r.x = o[0]; r.y = o[1]; r.z = o[2]; r.w = o[3];
        *(float4*)(x + (size_t)row * D + c) = r;
    }
}

// ---------------- layernorm fp32 -> bf16: one wave per row ----------------
__global__ __launch_bounds__(256) void ln_kernel(
    const float* __restrict__ x, const float* __restrict__ g,
    const float* __restrict__ b, unsigned short* __restrict__ h)
{
    int lane = threadIdx.x & 63;
    int row = blockIdx.x * 4 + (threadIdx.x >> 6);
    const float* xr = x + (size_t)row * D + lane * 8;
    float4 v0 = *(const float4*)(xr);
    float4 v1 = *(const float4*)(xr + 4);
    float s = v0.x + v0.y + v0.z + v0.w + v1.x + v1.y + v1.z + v1.w;
#pragma unroll
    for (int off = 32; off; off >>= 1) s += __shfl_xor(s, off, 64);
    float m = s * (1.0f / D);
    float d0 = v0.x - m, d1 = v0.y - m, d2 = v0.z - m, d3 = v0.w - m;
    float d4 = v1.x - m, d5 = v1.y - m, d6 = v1.z - m, d7 = v1.w - m;
    float ss = d0*d0 + d1*d1 + d2*d2 + d3*d3 + d4*d4 + d5*d5 + d6*d6 + d7*d7;
#pragma unroll
    for (int off = 32; off; off >>= 1) ss += __shfl_xor(ss, off, 64);
    float inv = rsqrtf(ss * (1.0f / D) + EPS);
    const float* gp = g + lane * 8;
    const float* bp = b + lane * 8;
    float4 g0 = *(const float4*)(gp), g1 = *(const float4*)(gp + 4);
    float4 b0 = *(const float4*)(bp), b1 = *(const float4*)(bp + 4);
    uint4 o;
    o.x = pack2(d0 * inv * g0.x + b0.x, d1 * inv * g0.y + b0.y);
    o.y = pack2(d2 * inv * g0.z + b0.z, d3 * inv * g0.w + b0.w);
    o.z = pack2(d4 * inv * g1.x + b1.x, d5 * inv * g1.y + b1.y);
    o.w = pack2(d6 * inv * g1.z + b1.z, d7 * inv * g1.w + b1.w);
    *(uint4*)(h + (size_t)row * D + lane * 8) = o;
}

// ---------------- bf16 MFMA GEMM: acc = A(bf16 MxK) @ W(bf16 NxK)^T ----------------
// 2-phase double-buffered pipeline, BK=64, XOR-swizzled LDS (R3/R4 validated).
// R9: BN template param. BM=64 GEMMs (Wo/FFN2) move BN 128->64 -> grid 512 =
// 2 blocks/CU. R8 counters showed them at Occupancy 9%, MfmaUtil 6%, HBM 14%:
// latency-bound with ZERO TLP (1 block/CU) — while one block sits in its
// barrier drain, the co-resident block now computes (m114 overlap). No
// sync-structure change (R5's in-block pipeline attempt was neutral).
// OMODE 0: C fp32 [M][N] = acc + bias + X (residual)
// OMODE 1: C bf16 [M][N] = relu(acc + bias)
// OMODE 2: fused QKV (N=1536), fragment-linear outputs for attn.
template<int OMODE, int BM, int BN>
__global__ __launch_bounds__(256) void gemm_bf16(
    const unsigned short* __restrict__ A, const unsigned short* __restrict__ W,
    const float* __restrict__ bias, const float* __restrict__ X,
    void* __restrict__ C, void* __restrict__ C2, void* __restrict__ C3,
    int M, int N, int K)
{
    constexpr int WM = BM / 64;       // 2 or 1
    constexpr int WN = 4 / WM;        // 2 or 4
    constexpr int NI = BN / (WN * 16); // 16-col frags per wave
    __shared__ __align__(16) unsigned short As[2][BM * 64];
    __shared__ __align__(16) unsigned short Bs[2][BN * 64];
    const int tid = threadIdx.x;
    const int wave = tid >> 6, lane = tid & 63;
    const int quad = lane >> 4, l16 = lane & 15;
    const int wm = wave / WN, wn = wave % WN;
    const int bm = blockIdx.y * BM, bn = blockIdx.x * BN;

    // staging: thread t covers row (t>>3) of each 32-row group, 8 shorts.
    // source column chunk is XOR-swizzled so linear LDS holds swizzled data.
    const int rS  = tid >> 3;
    const int csw = (((tid & 7) ^ (rS & 7)) << 3);
    const unsigned short* Asrc = A + (size_t)(bm + rS) * K + csw;
    const unsigned short* Bsrc = W + (size_t)(bn + rS) * K + csw;

    f32x4 acc[4][NI];
#pragma unroll
    for (int mi = 0; mi < 4; ++mi)
#pragma unroll
        for (int ni = 0; ni < NI; ++ni) acc[mi][ni] = (f32x4){0.f, 0.f, 0.f, 0.f};

    const int nt = K >> 6;

    // prologue: stage tile 0
#pragma unroll
    for (int i = 0; i < BM / 32; ++i)
        gl_lds16(Asrc + (size_t)(i * 32) * K, &As[0][i * 2048 + tid * 8]);
#pragma unroll
    for (int i = 0; i < BN / 32; ++i)
        gl_lds16(Bsrc + (size_t)(i * 32) * K, &Bs[0][i * 2048 + tid * 8]);
    __syncthreads();

    for (int t = 0; t < nt; ++t) {
        const int cur = t & 1;
        if (t + 1 < nt) {
            const int k0 = (t + 1) << 6;
#pragma unroll
            for (int i = 0; i < BM / 32; ++i)
                gl_lds16(Asrc + (size_t)(i * 32) * K + k0, &As[cur ^ 1][i * 2048 + tid * 8]);
#pragma unroll
            for (int i = 0; i < BN / 32; ++i)
                gl_lds16(Bsrc + (size_t)(i * 32) * K + k0, &Bs[cur ^ 1][i * 2048 + tid * 8]);
        }
#pragma unroll
        for (int kc = 0; kc < 2; ++kc) {
            const int gch = (kc << 2) | quad;   // global col chunk this quad wants
            bf16x8 af[4], bfr[NI];
#pragma unroll
            for (int mi = 0; mi < 4; ++mi) {
                const int ra = wm * 64 + mi * 16 + l16;
                af[mi] = *(const bf16x8*)&As[cur][ra * 64 + ((gch ^ (ra & 7)) << 3)];
            }
#pragma unroll
            for (int ni = 0; ni < NI; ++ni) {
                const int rb = wn * (BN / WN) + ni * 16 + l16;
                bfr[ni] = *(const bf16x8*)&Bs[cur][rb * 64 + ((gch ^ (rb & 7)) << 3)];
            }
#pragma unroll
            for (int mi = 0; mi < 4; ++mi)
#pragma unroll
                for (int ni = 0; ni < NI; ++ni)
                    acc[mi][ni] = __builtin_amdgcn_mfma_f32_16x16x32_bf16(
                        af[mi], bfr[ni], acc[mi][ni], 0, 0, 0);
        }
        __syncthreads();   // drains vmcnt(0): next tile landed, cur reads done
    }

    const int er = bm + wm * 64;
    const int ec = bn + wn * (BN / WN);

    if (OMODE == 0) {
        float* Cf = (float*)C;
#pragma unroll
        for (int ni = 0; ni < NI; ++ni) {
            int c = ec + ni * 16 + l16;
            float bv = bias[c];
#pragma unroll
            for (int mi = 0; mi < 4; ++mi)
#pragma unroll
                for (int r = 0; r < 4; ++r) {
                    int m = er + mi * 16 + quad * 4 + r;
                    Cf[(size_t)m * N + c] = acc[mi][ni][r] + bv + X[(size_t)m * N + c];
                }
        }
    } else if (OMODE == 1) {
        unsigned short* Cb = (unsigned short*)C;
#pragma unroll
        for (int ni = 0; ni < NI; ++ni) {
            int c = ec + ni * 16 + l16;
            float bv = bias[c];
#pragma unroll
            for (int mi = 0; mi < 4; ++mi)
#pragma unroll
                for (int r = 0; r < 4; ++r) {
                    int m = er + mi * 16 + quad * 4 + r;
                    Cb[(size_t)m * N + c] = f2bf(fmaxf(acc[mi][ni][r] + bv, 0.f));
                }
        }
    } else {
        if (bn < 512) {            // Q (scaled), fragment-linear
            unsigned short* Qp = (unsigned short*)C;
#pragma unroll
            for (int ni = 0; ni < NI; ++ni) {
                int c = ec + ni * 16 + l16;
                float bv = bias[c];
                int hh = c >> 6, dd = c & 63;
                size_t cbase = (size_t)(dd >> 5) * 512 + (size_t)((dd >> 3) & 3) * 128 + (dd & 7);
#pragma unroll
                for (int mi = 0; mi < 4; ++mi)
#pragma unroll
                    for (int r = 0; r < 4; ++r) {
                        int m = er + mi * 16 + quad * 4 + r;
                        int b = m >> 10, t = m & 1023;
                        Qp[(size_t)(b * 8 + hh) * 65536 + (size_t)(t >> 4) * 1024
                           + cbase + (size_t)(t & 15) * 8] =
                            f2bf((acc[mi][ni][r] + bv) * INV_SCALE);
                    }
            }
        } else if (bn < 1024) {    // K, fragment-linear
            unsigned short* Kp = (unsigned short*)C2;
#pragma unroll
            for (int ni = 0; ni < NI; ++ni) {
                int c = ec + ni * 16 + l16;
                float bv = bias[c];
                int c2 = c - 512;
                int hh = c2 >> 6, dd = c2 & 63;
                size_t cbase = (size_t)(dd >> 5) * 512 + (size_t)((dd >> 3) & 3) * 128 + (dd & 7);
#pragma unroll
                for (int mi = 0; mi < 4; ++mi)
#pragma unroll
                    for (int r = 0; r < 4; ++r) {
                        int m = er + mi * 16 + quad * 4 + r;
                        int b = m >> 10, t = m & 1023;
                        Kp[(size_t)(b * 8 + hh) * 65536 + (size_t)(t >> 4) * 1024
                           + cbase + (size_t)(t & 15) * 8] =
                            f2bf(acc[mi][ni][r] + bv);
                    }
            }
        } else {                   // V, fragment-linear (transposed consumption)
            unsigned short* Vp = (unsigned short*)C3;
#pragma unroll
            for (int ni = 0; ni < NI; ++ni) {
                int c = ec + ni * 16 + l16;
                float bv = bias[c];
                int c2 = c - 1024;
                int hh = c2 >> 6, dd = c2 & 63;
                size_t dbase = (size_t)(dd >> 4) * 16384 + (size_t)(dd & 15) * 8;
#pragma unroll
                for (int mi = 0; mi < 4; ++mi) {
                    int t0 = er + mi * 16 + quad * 4;
                    int b = t0 >> 10, tt = t0 & 1023;
                    ushort4 o;
                    o.x = f2bf(acc[mi][ni][0] + bv);
                    o.y = f2bf(acc[mi][ni][1] + bv);
                    o.z = f2bf(acc[mi][ni][2] + bv);
                    o.w = f2bf(acc[mi][ni][3] + bv);
                    *(ushort4*)(Vp + (size_t)(b * 8 + hh) * 65536 + dbase
                                + (size_t)(tt >> 5) * 512
                                + (size_t)((tt >> 3) & 3) * 128 + (tt & 7)) = o;
                }
            }
        }
    }
}

// ---------------- flash attention: split-K, QROWS=32 per block (R4 best) ----
// Fragment-linear layouts + asm-pinned double-buffered private loads.
__global__ __launch_bounds__(256, 1) void attn_mfma(
    const unsigned short* __restrict__ Qb, const unsigned short* __restrict__ Kb,
    const unsigned short* __restrict__ Vt, unsigned short* __restrict__ av)
{
    __shared__ float Ol[4][32][68];   // [wave][q][d] fp32 partial O (+pad)
    __shared__ float Ls[4][32];       // [wave][q] partial denominators
    const int tid = threadIdx.x;
    const int wave = tid >> 6, lane = tid & 63;
    const int quad = lane >> 4, l16 = lane & 15;
    const int bh = blockIdx.x & 31;          // xcd = bh % 8 -> K/V L2-resident per XCD
    const int b = bh >> 3, h = bh & 7;
    const int q0 = (blockIdx.x >> 5) * 32;   // 32 q-tiles of 32 rows

    const unsigned short* qp = Qb + (size_t)bh * 65536 + (size_t)(q0 >> 4) * 1024 + lane * 8;
    const unsigned short* kbase = Kb + (size_t)bh * 65536 + lane * 8;
    const unsigned short* vbase = Vt + (size_t)bh * 65536 + lane * 8;

    // bpermute byte addresses: pull from quad (2q)&3 / (2q+1)&3 at same l16
    const int sA  = ((((2 * quad) & 3) << 4) + l16) << 2;
    const int sB2 = ((((2 * quad + 1) & 3) << 4) + l16) << 2;

    f32x4 o[2][4];
#pragma unroll
    for (int qs = 0; qs < 2; ++qs)
#pragma unroll
        for (int nf = 0; nf < 4; ++nf) o[qs][nf] = (f32x4){0.f, 0.f, 0.f, 0.f};
    float lp[2] = {0.f, 0.f};   // per-lane partial column (=query) sums

    const int j0 = wave * 256;

    // ---- prologue: issue Q (4) + buffer0 K/V (16) loads; 20 in flight ----
    bf16x8 qf[2][2];
    gload16(qf[0][0], qp);
    gload16(qf[0][1], qp + 512);
    gload16(qf[1][0], qp + 1024);
    gload16(qf[1][1], qp + 1536);

    bf16x8 kc[2][8], vf[2][8];
#pragma unroll
    for (int nf = 0; nf < 4; ++nf) {
        gload16(kc[0][2 * nf],     kbase + (size_t)j0 * 64 + nf * 1024);
        gload16(kc[0][2 * nf + 1], kbase + (size_t)j0 * 64 + nf * 1024 + 512);
        gload16(vf[0][2 * nf],     vbase + (size_t)j0 * 16 + nf * 16384);
        gload16(vf[0][2 * nf + 1], vbase + (size_t)j0 * 16 + nf * 16384 + 512);
    }

#pragma unroll
    for (int it = 0; it < 4; ++it) {
        const int cur = it & 1, nxt = cur ^ 1;
        // ---- issue next tile's 16 loads BEFORE waiting on current ----
        if (it < 3) {
            const int jn = j0 + (it + 1) * 64;
#pragma unroll
            for (int nf = 0; nf < 4; ++nf) {
                gload16(kc[nxt][2 * nf],     kbase + (size_t)jn * 64 + nf * 1024);
                gload16(kc[nxt][2 * nf + 1], kbase + (size_t)jn * 64 + nf * 1024 + 512);
                gload16(vf[nxt][2 * nf],     vbase + (size_t)jn * 16 + nf * 16384);
                gload16(vf[nxt][2 * nf + 1], vbase + (size_t)jn * 16 + nf * 16384 + 512);
            }
        }
        // ---- counted wait: current buffer (+Q at it=0) done, next 16 in flight ----
        if (it < 3) asm volatile("s_waitcnt vmcnt(16)" ::: "memory");
        else        asm volatile("s_waitcnt vmcnt(0)"  ::: "memory");
        __builtin_amdgcn_sched_barrier(0);
        // ---- S^T tiles (row=key, col=query), exp, pack — per (nf, qs) ----
        unsigned pk01[2][4], pk23[2][4];
#pragma unroll
        for (int nf = 0; nf < 4; ++nf)
#pragma unroll
            for (int qs = 0; qs < 2; ++qs) {
                f32x4 z = {0.f, 0.f, 0.f, 0.f};
                z = __builtin_amdgcn_mfma_f32_16x16x32_bf16(kc[cur][2 * nf], qf[qs][0], z, 0, 0, 0);
                z = __builtin_amdgcn_mfma_f32_16x16x32_bf16(kc[cur][2 * nf + 1], qf[qs][1], z, 0, 0, 0);
                float p0 = __expf(z[0]);
                float p1 = __expf(z[1]);
                float p2 = __expf(z[2]);
                float p3 = __expf(z[3]);
                lp[qs] += (p0 + p1) + (p2 + p3);
                pk01[qs][nf] = pack2(p0, p1);
                pk23[qs][nf] = pack2(p2, p3);
            }
        // ---- register-only C->A transform (validated), per q-subtile ----
#pragma unroll
        for (int qs = 0; qs < 2; ++qs) {
            union PU { unsigned d[4]; bf16x8 v; } f0, f1;
            unsigned a0, a1;
            a0 = (unsigned)__builtin_amdgcn_ds_bpermute(sA,  (int)pk01[qs][0]);
            a1 = (unsigned)__builtin_amdgcn_ds_bpermute(sA,  (int)pk01[qs][1]);
            f0.d[0] = (quad < 2) ? a0 : a1;
            a0 = (unsigned)__builtin_amdgcn_ds_bpermute(sA,  (int)pk23[qs][0]);
            a1 = (unsigned)__builtin_amdgcn_ds_bpermute(sA,  (int)pk23[qs][1]);
            f0.d[1] = (quad < 2) ? a0 : a1;
            a0 = (unsigned)__builtin_amdgcn_ds_bpermute(sB2, (int)pk01[qs][0]);
            a1 = (unsigned)__builtin_amdgcn_ds_bpermute(sB2, (int)pk01[qs][1]);
            f0.d[2] = (quad < 2) ? a0 : a1;
            a0 = (unsigned)__builtin_amdgcn_ds_bpermute(sB2, (int)pk23[qs][0]);
            a1 = (unsigned)__builtin_amdgcn_ds_bpermute(sB2, (int)pk23[qs][1]);
            f0.d[3] = (quad < 2) ? a0 : a1;
            a0 = (unsigned)__builtin_amdgcn_ds_bpermute(sA,  (int)pk01[qs][2]);
            a1 = (unsigned)__builtin_amdgcn_ds_bpermute(sA,  (int)pk01[qs][3]);
            f1.d[0] = (quad < 2) ? a0 : a1;
            a0 = (unsigned)__builtin_amdgcn_ds_bpermute(sA,  (int)pk23[qs][2]);
            a1 = (unsigned)__builtin_amdgcn_ds_bpermute(sA,  (int)pk23[qs][3]);
            f1.d[1] = (quad < 2) ? a0 : a1;
            a0 = (unsigned)__builtin_amdgcn_ds_bpermute(sB2, (int)pk01[qs][2]);
            a1 = (unsigned)__builtin_amdgcn_ds_bpermute(sB2, (int)pk01[qs][3]);
            f1.d[2] = (quad < 2) ? a0 : a1;
            a0 = (unsigned)__builtin_amdgcn_ds_bpermute(sB2, (int)pk23[qs][2]);
            a1 = (unsigned)__builtin_amdgcn_ds_bpermute(sB2, (int)pk23[qs][3]);
            f1.d[3] = (quad < 2) ? a0 : a1;
            // ---- O += P.V ----
#pragma unroll
            for (int nf = 0; nf < 4; ++nf) {
                o[qs][nf] = __builtin_amdgcn_mfma_f32_16x16x32_bf16(f0.v, vf[cur][2 * nf], o[qs][nf], 0, 0, 0);
                o[qs][nf] = __builtin_amdgcn_mfma_f32_16x16x32_bf16(f1.v, vf[cur][2 * nf + 1], o[qs][nf], 0, 0, 0);
            }
        }
    }
    // ---- write per-wave partials to LDS ----
#pragma unroll
    for (int qs = 0; qs < 2; ++qs)
#pragma unroll
        for (int nf = 0; nf < 4; ++nf)
#pragma unroll
            for (int r = 0; r < 4; ++r)
                Ol[wave][qs * 16 + quad * 4 + r][nf * 16 + l16] = o[qs][nf][r];
#pragma unroll
    for (int qs = 0; qs < 2; ++qs) {
        float ts = lp[qs];
        ts += __shfl_xor(ts, 16, 64);
        ts += __shfl_xor(ts, 32, 64);
        if (quad == 0) Ls[wave][qs * 16 + l16] = ts;
    }
    __syncthreads();
    // ---- combine: wave w handles d-frag nf=w, 32 q rows ----
#pragma unroll
    for (int half = 0; half < 2; ++half)
#pragma unroll
        for (int r = 0; r < 4; ++r) {
            int qq = half * 16 + quad * 4 + r;
            float denom = Ls[0][qq] + Ls[1][qq] + Ls[2][qq] + Ls[3][qq];
            float v = Ol[0][qq][wave * 16 + l16] + Ol[1][qq][wave * 16 + l16]
                    + Ol[2][qq][wave * 16 + l16] + Ol[3][qq][wave * 16 + l16];
            int q = q0 + qq;
            av[((size_t)(b * 1024 + q)) * D + h * 64 + wave * 16 + l16] =
                f2bf(v / denom);
        }
}

// ---------------- classifier ----------------
__global__ __launch_bounds__(256) void cls_kernel(
    const float* __restrict__ x, const float* __restrict__ Wc,
    const float* __restrict__ bc, float* __restrict__ out)
{
    int lane = threadIdx.x & 63;
    int row = blockIdx.x * 4 + (threadIdx.x >> 6);
    const float* xr = x + (size_t)row * D + lane * 8;
    float4 v0 = *(const float4*)xr;
    float4 v1 = *(const float4*)(xr + 4);
    float acc[10];
#pragma unroll
    for (int c = 0; c < 10; ++c) {
        const float* wr = Wc + c * D + lane * 8;
        float4 w0 = *(const float4*)wr;
        float4 w1 = *(const float4*)(wr + 4);
        acc[c] = v0.x*w0.x + v0.y*w0.y + v0.z*w0.z + v0.w*w0.w
               + v1.x*w1.x + v1.y*w1.y + v1.z*w1.z + v1.w*w1.w;
    }
#pragma unroll
    for (int c = 0; c < 10; ++c)
#pragma unroll
        for (int off = 32; off; off >>= 1) acc[c] += __shfl_xor(acc[c], off, 64);
    if (lane == 0) {
#pragma unroll
        for (int c = 0; c < 10; ++c) out[(size_t)row * 10 + c] = acc[c] + bc[c];
    }
}

extern "C" void kernel_launch(void* const* d_in, const int* in_sizes, int n_in,
                              void* d_out, int out_size, void* d_ws, size_t ws_size,
                              hipStream_t stream)
{
    const int*   tokens = (const int*)  d_in[0];
    const float* emb    = (const float*)d_in[1];
    const float* Wq     = (const float*)d_in[2];
    const float* bq     = (const float*)d_in[3];
    const float* Wkv    = (const float*)d_in[4];
    const float* bkv    = (const float*)d_in[5];
    const float* Wo     = (const float*)d_in[6];
    const float* bo     = (const float*)d_in[7];
    const float* ln1g   = (const float*)d_in[8];
    const float* ln1b   = (const float*)d_in[9];
    const float* W1     = (const float*)d_in[10];
    const float* b1     = (const float*)d_in[11];
    const float* W2     = (const float*)d_in[12];
    const float* b2     = (const float*)d_in[13];
    const float* ln2g   = (const float*)d_in[14];
    const float* ln2b   = (const float*)d_in[15];
    const float* Wc     = (const float*)d_in[16];
    const float* bc     = (const float*)d_in[17];
    float* out = (float*)d_out;

    // workspace (~64 MB; harness poisons >=268MB per fillBuffer WRITE_SIZE):
    // x fp32 8MB | hb bf16 4MB | Qb 4 | Kb 4 | Vt 4 | avb 4 (f1b aliases Qb..)
    // | wl bf16 6x6MB = 36MB | wbias fp32 36KB
    float* x  = (float*)d_ws;
    unsigned short* hb  = (unsigned short*)(x + (size_t)MTOK * D);
    unsigned short* Qb  = hb  + (size_t)MTOK * D;
    unsigned short* Kb  = Qb  + (size_t)32 * 1024 * 64;
    unsigned short* Vt  = Kb  + (size_t)32 * 1024 * 64;
    unsigned short* avb = Vt  + (size_t)32 * 1024 * 64;
    unsigned short* f1b = Qb;                              // [4096][2048] bf16 = 16 MB
    unsigned short* wl  = avb + (size_t)32 * 1024 * 64;    // all-layer bf16 weights (36 MB)
    float* wbias = (float*)(wl + (size_t)6 * 3145728);     // combined [bq;bkv] x 6 (36 KB)

    // per-layer wl layout: [Wq;Wkv] contiguous 1536x512, then Wo, W1, W2
    const size_t oWo = 786432, oW1 = 1048576, oW2 = 2097152, LW = 3145728;

    prep_kernel<<<11265, 256, 0, stream>>>(
        tokens, emb, Wq, Wkv, Wo, W1, W2, bq, bkv, wl, wbias, x);

    for (int l = 0; l < NLAYER; ++l) {
        const unsigned short* wll = wl + (size_t)l * LW;
        ln_kernel<<<MTOK / 4, 256, 0, stream>>>(x, ln1g + l * D, ln1b + l * D, hb);
        gemm_bf16<2,128,128><<<dim3(12, 32), 256, 0, stream>>>(
            hb, wll, wbias + l * 1536, nullptr, Qb, Kb, Vt, MTOK, 1536, 512);
        attn_mfma<<<1024, 256, 0, stream>>>(Qb, Kb, Vt, avb);
        gemm_bf16<0,64,64><<<dim3(8, 64), 256, 0, stream>>>(
            avb, wll + oWo, bo + l * D, x, x, nullptr, nullptr, MTOK, D, D);
        ln_kernel<<<MTOK / 4, 256, 0, stream>>>(x, ln2g + l * D, ln2b + l * D, hb);
        gemm_bf16<1,128,128><<<dim3(16, 32), 256, 0, stream>>>(
            hb, wll + oW1, b1 + l * 4 * D, nullptr, f1b, nullptr, nullptr, MTOK, 4 * D, D);
        gemm_bf16<0,64,64><<<dim3(8, 64), 256, 0, stream>>>(
            f1b, wll + oW2, b2 + l * D, x, x, nullptr, nullptr, MTOK, D, 4 * D);
    }

    cls_kernel<<<MTOK / 4, 256, 0, stream>>>(x, Wc, bc, out);
}

// Round 10
// 681.112 us; speedup vs baseline: 1.4983x; 1.0500x over previous
//
#include <hip/hip_runtime.h>
#include <math.h>

#define D 512
#define HEADS 8
#define NLAYER 6
#define LSEQ 1024
#define BATCH 4
#define DKH 64
#define MTOK (BATCH*LSEQ)   // 4096 tokens
#define EPS 1e-5f
#define EMB_SCALE 22.627416997969522f  // sqrt(512)
#define INV_SCALE 0.125f               // 1/sqrt(64)

typedef __attribute__((ext_vector_type(8))) __bf16 bf16x8;
typedef __attribute__((ext_vector_type(4))) float f32x4;

__device__ __forceinline__ unsigned short f2bf(float x) {
    union { float f; unsigned u; } v; v.f = x;
    unsigned r = (v.u + 0x7FFFu + ((v.u >> 16) & 1u)) >> 16;
    return (unsigned short)r;
}
__device__ __forceinline__ unsigned pack2(float a, float b) {
    return (unsigned)f2bf(a) | ((unsigned)f2bf(b) << 16);
}
__device__ __forceinline__ void gl_lds16(const unsigned short* g, unsigned short* l) {
    __builtin_amdgcn_global_load_lds(
        (const __attribute__((address_space(1))) unsigned*)g,
        (__attribute__((address_space(3))) unsigned*)l, 16, 0, 0);
}
// asm 16B global load (attn): volatile asm cannot be sunk -> pipeline holds.
__device__ __forceinline__ void gload16(bf16x8& d, const unsigned short* p) {
    asm volatile("global_load_dwordx4 %0, %1, off" : "=v"(d) : "v"(p));
}

// ---------------- prep: ALL-layer weight fp32->bf16 + biases + embedding ----
__global__ __launch_bounds__(256) void prep_kernel(
    const int* __restrict__ tokens, const float* __restrict__ emb,
    const float* __restrict__ Wq, const float* __restrict__ Wkv,
    const float* __restrict__ Wo, const float* __restrict__ W1,
    const float* __restrict__ W2, const float* __restrict__ bq,
    const float* __restrict__ bkv, unsigned short* __restrict__ wl,
    float* __restrict__ wbias, float* __restrict__ x)
{
    const int bid = blockIdx.x;
    if (bid < 9216) {                       // weight conversion, 6 layers
        const int l = bid / 1536;
        const int e = (bid - l * 1536) * 2048 + threadIdx.x * 8;
        const float* src;
        if      (e < 262144)  src = Wq  + (size_t)l * 262144  + e;
        else if (e < 786432)  src = Wkv + (size_t)l * 524288  + (e - 262144);
        else if (e < 1048576) src = Wo  + (size_t)l * 262144  + (e - 786432);
        else if (e < 2097152) src = W1  + (size_t)l * 1048576 + (e - 1048576);
        else                  src = W2  + (size_t)l * 1048576 + (e - 2097152);
        float4 a = *(const float4*)src;
        float4 b = *(const float4*)(src + 4);
        uint4 o;
        o.x = pack2(a.x, a.y); o.y = pack2(a.z, a.w);
        o.z = pack2(b.x, b.y); o.w = pack2(b.z, b.w);
        *(uint4*)(wl + (size_t)l * 3145728 + e) = o;
    } else if (bid == 9216) {               // combined QKV biases, 6 layers
        for (int i = threadIdx.x; i < 9216; i += 256) {
            int l = i / 1536, j = i - l * 1536;
            wbias[i] = (j < 512) ? bq[l * 512 + j] : bkv[l * 1024 + (j - 512)];
        }
    } else {                                // embedding + positional encoding
        int row = (bid - 9217) * 2 + (threadIdx.x >> 7);
        int pos = row & (LSEQ - 1);
        int tok = tokens[row];
        int c = (threadIdx.x & 127) * 4;
        float4 e = *(const float4*)(emb + (size_t)tok * D + c);
        float o[4] = {e.x, e.y, e.z, e.w};
#pragma unroll
        for (int i = 0; i < 4; ++i) {
            int col = c + i;
            int ii = col & ~1;
            float dv = expf(-(float)ii * (9.210340371976184f / (float)D));
            float a = (float)pos * dv;
            float pe = (col & 1) ? cosf(a) : sinf(a);
            o[i] = o[i] * EMB_SCALE + pe;
        }
        float4 r; r.x = o[0]; r.y = o[1]; r.z = o[2]; r.w = o[3];
        *(float4*)(x + (size_t)row * D + c) = r;
    }
}

// ---------------- layernorm fp32 -> bf16: one wave per row ----------------
__global__ __launch_bounds__(256) void ln_kernel(
    const float* __restrict__ x, const float* __restrict__ g,
    const float* __restrict__ b, unsigned short* __restrict__ h)
{
    int lane = threadIdx.x & 63;
    int row = blockIdx.x * 4 + (threadIdx.x >> 6);
    const float* xr = x + (size_t)row * D + lane * 8;
    float4 v0 = *(const float4*)(xr);
    float4 v1 = *(const float4*)(xr + 4);
    float s = v0.x + v0.y + v0.z + v0.w + v1.x + v1.y + v1.z + v1.w;
#pragma unroll
    for (int off = 32; off; off >>= 1) s += __shfl_xor(s, off, 64);
    float m = s * (1.0f / D);
    float d0 = v0.x - m, d1 = v0.y - m, d2 = v0.z - m, d3 = v0.w - m;
    float d4 = v1.x - m, d5 = v1.y - m, d6 = v1.z - m, d7 = v1.w - m;
    float ss = d0*d0 + d1*d1 + d2*d2 + d3*d3 + d4*d4 + d5*d5 + d6*d6 + d7*d7;
#pragma unroll
    for (int off = 32; off; off >>= 1) ss += __shfl_xor(ss, off, 64);
    float inv = rsqrtf(ss * (1.0f / D) + EPS);
    const float* gp = g + lane * 8;
    const float* bp = b + lane * 8;
    float4 g0 = *(const float4*)(gp), g1 = *(const float4*)(gp + 4);
    float4 b0 = *(const float4*)(bp), b1 = *(const float4*)(bp + 4);
    uint4 o;
    o.x = pack2(d0 * inv * g0.x + b0.x, d1 * inv * g0.y + b0.y);
    o.y = pack2(d2 * inv * g0.z + b0.z, d3 * inv * g0.w + b0.w);
    o.z = pack2(d4 * inv * g1.x + b1.x, d5 * inv * g1.y + b1.y);
    o.w = pack2(d6 * inv * g1.z + b1.z, d7 * inv * g1.w + b1.w);
    *(uint4*)(h + (size_t)row * D + lane * 8) = o;
}

// ---------------- bf16 MFMA GEMM: acc = A(bf16 MxK) @ W(bf16 NxK)^T ----------------
// 2-phase double-buffered pipeline, XOR-swizzled LDS (R3/R4/R9 validated).
// R10: BK template param. BM=64 GEMMs (Wo/FFN2) use BK=128 -> barrier-drain
// pairs halve (FFN2 32->16, Wo 8->4); LDS 64KB keeps the R9-proven 2
// blocks/CU. QKV moves BN 128->64 -> grid 768 = exactly 3 blocks/CU (was
// 1.5: half the CUs idled half the time); total staged bytes identical.
// Swizzle generalizes: chunk = tid%(BK/8), row = tid/(BK/8); XOR with row&7
// spreads ds_read_b128 over all 32 banks at 2-way (free) for BK=64 and 128.
// OMODE 0: C fp32 [M][N] = acc + bias + X (residual)
// OMODE 1: C bf16 [M][N] = relu(acc + bias)
// OMODE 2: fused QKV (N=1536), fragment-linear outputs for attn.
template<int OMODE, int BM, int BN, int BK>
__global__ __launch_bounds__(256) void gemm_bf16(
    const unsigned short* __restrict__ A, const unsigned short* __restrict__ W,
    const float* __restrict__ bias, const float* __restrict__ X,
    void* __restrict__ C, void* __restrict__ C2, void* __restrict__ C3,
    int M, int N, int K)
{
    constexpr int WM = BM / 64;        // 2 or 1
    constexpr int WN = 4 / WM;         // 2 or 4
    constexpr int NI = BN / (WN * 16); // 16-col frags per wave
    constexpr int CPB = BK / 8;        // 8-short chunks per row
    constexpr int RPP = 2048 / BK;     // rows covered per 256-thread pass
    __shared__ __align__(16) unsigned short As[2][BM * BK];
    __shared__ __align__(16) unsigned short Bs[2][BN * BK];
    const int tid = threadIdx.x;
    const int wave = tid >> 6, lane = tid & 63;
    const int quad = lane >> 4, l16 = lane & 15;
    const int wm = wave / WN, wn = wave % WN;
    const int bm = blockIdx.y * BM, bn = blockIdx.x * BN;

    // staging: thread covers row rS of each RPP-row group, chunk ch (8 shorts).
    // source column chunk is XOR-swizzled so linear LDS holds swizzled data:
    // LDS[r][c] = G[r][c ^ (r&7)]; reads apply the same XOR.
    const int rS  = tid / CPB;
    const int ch  = tid % CPB;
    const int csw = ((ch ^ (rS & 7)) << 3);
    const unsigned short* Asrc = A + (size_t)(bm + rS) * K + csw;
    const unsigned short* Bsrc = W + (size_t)(bn + rS) * K + csw;

    f32x4 acc[4][NI];
#pragma unroll
    for (int mi = 0; mi < 4; ++mi)
#pragma unroll
        for (int ni = 0; ni < NI; ++ni) acc[mi][ni] = (f32x4){0.f, 0.f, 0.f, 0.f};

    const int nt = K / BK;

    // prologue: stage tile 0
#pragma unroll
    for (int i = 0; i < BM / RPP; ++i)
        gl_lds16(Asrc + (size_t)(i * RPP) * K, &As[0][i * 2048 + tid * 8]);
#pragma unroll
    for (int i = 0; i < BN / RPP; ++i)
        gl_lds16(Bsrc + (size_t)(i * RPP) * K, &Bs[0][i * 2048 + tid * 8]);
    __syncthreads();

    for (int t = 0; t < nt; ++t) {
        const int cur = t & 1;
        if (t + 1 < nt) {
            const int k0 = (t + 1) * BK;
#pragma unroll
            for (int i = 0; i < BM / RPP; ++i)
                gl_lds16(Asrc + (size_t)(i * RPP) * K + k0, &As[cur ^ 1][i * 2048 + tid * 8]);
#pragma unroll
            for (int i = 0; i < BN / RPP; ++i)
                gl_lds16(Bsrc + (size_t)(i * RPP) * K + k0, &Bs[cur ^ 1][i * 2048 + tid * 8]);
        }
#pragma unroll
        for (int kc = 0; kc < BK / 32; ++kc) {
            const int gch = (kc << 2) | quad;   // global col chunk this quad wants
            bf16x8 af[4], bfr[NI];
#pragma unroll
            for (int mi = 0; mi < 4; ++mi) {
                const int ra = wm * 64 + mi * 16 + l16;
                af[mi] = *(const bf16x8*)&As[cur][ra * BK + ((gch ^ (ra & 7)) << 3)];
            }
#pragma unroll
            for (int ni = 0; ni < NI; ++ni) {
                const int rb = wn * (BN / WN) + ni * 16 + l16;
                bfr[ni] = *(const bf16x8*)&Bs[cur][rb * BK + ((gch ^ (rb & 7)) << 3)];
            }
#pragma unroll
            for (int mi = 0; mi < 4; ++mi)
#pragma unroll
                for (int ni = 0; ni < NI; ++ni)
                    acc[mi][ni] = __builtin_amdgcn_mfma_f32_16x16x32_bf16(
                        af[mi], bfr[ni], acc[mi][ni], 0, 0, 0);
        }
        __syncthreads();   // drains vmcnt(0): next tile landed, cur reads done
    }

    const int er = bm + wm * 64;
    const int ec = bn + wn * (BN / WN);

    if (OMODE == 0) {
        float* Cf = (float*)C;
#pragma unroll
        for (int ni = 0; ni < NI; ++ni) {
            int c = ec + ni * 16 + l16;
            float bv = bias[c];
#pragma unroll
            for (int mi = 0; mi < 4; ++mi)
#pragma unroll
                for (int r = 0; r < 4; ++r) {
                    int m = er + mi * 16 + quad * 4 + r;
                    Cf[(size_t)m * N + c] = acc[mi][ni][r] + bv + X[(size_t)m * N + c];
                }
        }
    } else if (OMODE == 1) {
        unsigned short* Cb = (unsigned short*)C;
#pragma unroll
        for (int ni = 0; ni < NI; ++ni) {
            int c = ec + ni * 16 + l16;
            float bv = bias[c];
#pragma unroll
            for (int mi = 0; mi < 4; ++mi)
#pragma unroll
                for (int r = 0; r < 4; ++r) {
                    int m = er + mi * 16 + quad * 4 + r;
                    Cb[(size_t)m * N + c] = f2bf(fmaxf(acc[mi][ni][r] + bv, 0.f));
                }
        }
    } else {
        if (bn < 512) {            // Q (scaled), fragment-linear
            unsigned short* Qp = (unsigned short*)C;
#pragma unroll
            for (int ni = 0; ni < NI; ++ni) {
                int c = ec + ni * 16 + l16;
                float bv = bias[c];
                int hh = c >> 6, dd = c & 63;
                size_t cbase = (size_t)(dd >> 5) * 512 + (size_t)((dd >> 3) & 3) * 128 + (dd & 7);
#pragma unroll
                for (int mi = 0; mi < 4; ++mi)
#pragma unroll
                    for (int r = 0; r < 4; ++r) {
                        int m = er + mi * 16 + quad * 4 + r;
                        int b = m >> 10, t = m & 1023;
                        Qp[(size_t)(b * 8 + hh) * 65536 + (size_t)(t >> 4) * 1024
                           + cbase + (size_t)(t & 15) * 8] =
                            f2bf((acc[mi][ni][r] + bv) * INV_SCALE);
                    }
            }
        } else if (bn < 1024) {    // K, fragment-linear
            unsigned short* Kp = (unsigned short*)C2;
#pragma unroll
            for (int ni = 0; ni < NI; ++ni) {
                int c = ec + ni * 16 + l16;
                float bv = bias[c];
                int c2 = c - 512;
                int hh = c2 >> 6, dd = c2 & 63;
                size_t cbase = (size_t)(dd >> 5) * 512 + (size_t)((dd >> 3) & 3) * 128 + (dd & 7);
#pragma unroll
                for (int mi = 0; mi < 4; ++mi)
#pragma unroll
                    for (int r = 0; r < 4; ++r) {
                        int m = er + mi * 16 + quad * 4 + r;
                        int b = m >> 10, t = m & 1023;
                        Kp[(size_t)(b * 8 + hh) * 65536 + (size_t)(t >> 4) * 1024
                           + cbase + (size_t)(t & 15) * 8] =
                            f2bf(acc[mi][ni][r] + bv);
                    }
            }
        } else {                   // V, fragment-linear (transposed consumption)
            unsigned short* Vp = (unsigned short*)C3;
#pragma unroll
            for (int ni = 0; ni < NI; ++ni) {
                int c = ec + ni * 16 + l16;
                float bv = bias[c];
                int c2 = c - 1024;
                int hh = c2 >> 6, dd = c2 & 63;
                size_t dbase = (size_t)(dd >> 4) * 16384 + (size_t)(dd & 15) * 8;
#pragma unroll
                for (int mi = 0; mi < 4; ++mi) {
                    int t0 = er + mi * 16 + quad * 4;
                    int b = t0 >> 10, tt = t0 & 1023;
                    ushort4 o;
                    o.x = f2bf(acc[mi][ni][0] + bv);
                    o.y = f2bf(acc[mi][ni][1] + bv);
                    o.z = f2bf(acc[mi][ni][2] + bv);
                    o.w = f2bf(acc[mi][ni][3] + bv);
                    *(ushort4*)(Vp + (size_t)(b * 8 + hh) * 65536 + dbase
                                + (size_t)(tt >> 5) * 512
                                + (size_t)((tt >> 3) & 3) * 128 + (tt & 7)) = o;
                }
            }
        }
    }
}

// ---------------- flash attention: split-K, QROWS=32 per block (R4 best) ----
// Fragment-linear layouts + asm-pinned double-buffered private loads.
__global__ __launch_bounds__(256, 1) void attn_mfma(
    const unsigned short* __restrict__ Qb, const unsigned short* __restrict__ Kb,
    const unsigned short* __restrict__ Vt, unsigned short* __restrict__ av)
{
    __shared__ float Ol[4][32][68];   // [wave][q][d] fp32 partial O (+pad)
    __shared__ float Ls[4][32];       // [wave][q] partial denominators
    const int tid = threadIdx.x;
    const int wave = tid >> 6, lane = tid & 63;
    const int quad = lane >> 4, l16 = lane & 15;
    const int bh = blockIdx.x & 31;          // xcd = bh % 8 -> K/V L2-resident per XCD
    const int b = bh >> 3, h = bh & 7;
    const int q0 = (blockIdx.x >> 5) * 32;   // 32 q-tiles of 32 rows

    const unsigned short* qp = Qb + (size_t)bh * 65536 + (size_t)(q0 >> 4) * 1024 + lane * 8;
    const unsigned short* kbase = Kb + (size_t)bh * 65536 + lane * 8;
    const unsigned short* vbase = Vt + (size_t)bh * 65536 + lane * 8;

    // bpermute byte addresses: pull from quad (2q)&3 / (2q+1)&3 at same l16
    const int sA  = ((((2 * quad) & 3) << 4) + l16) << 2;
    const int sB2 = ((((2 * quad + 1) & 3) << 4) + l16) << 2;

    f32x4 o[2][4];
#pragma unroll
    for (int qs = 0; qs < 2; ++qs)
#pragma unroll
        for (int nf = 0; nf < 4; ++nf) o[qs][nf] = (f32x4){0.f, 0.f, 0.f, 0.f};
    float lp[2] = {0.f, 0.f};   // per-lane partial column (=query) sums

    const int j0 = wave * 256;

    // ---- prologue: issue Q (4) + buffer0 K/V (16) loads; 20 in flight ----
    bf16x8 qf[2][2];
    gload16(qf[0][0], qp);
    gload16(qf[0][1], qp + 512);
    gload16(qf[1][0], qp + 1024);
    gload16(qf[1][1], qp + 1536);

    bf16x8 kc[2][8], vf[2][8];
#pragma unroll
    for (int nf = 0; nf < 4; ++nf) {
        gload16(kc[0][2 * nf],     kbase + (size_t)j0 * 64 + nf * 1024);
        gload16(kc[0][2 * nf + 1], kbase + (size_t)j0 * 64 + nf * 1024 + 512);
        gload16(vf[0][2 * nf],     vbase + (size_t)j0 * 16 + nf * 16384);
        gload16(vf[0][2 * nf + 1], vbase + (size_t)j0 * 16 + nf * 16384 + 512);
    }

#pragma unroll
    for (int it = 0; it < 4; ++it) {
        const int cur = it & 1, nxt = cur ^ 1;
        // ---- issue next tile's 16 loads BEFORE waiting on current ----
        if (it < 3) {
            const int jn = j0 + (it + 1) * 64;
#pragma unroll
            for (int nf = 0; nf < 4; ++nf) {
                gload16(kc[nxt][2 * nf],     kbase + (size_t)jn * 64 + nf * 1024);
                gload16(kc[nxt][2 * nf + 1], kbase + (size_t)jn * 64 + nf * 1024 + 512);
                gload16(vf[nxt][2 * nf],     vbase + (size_t)jn * 16 + nf * 16384);
                gload16(vf[nxt][2 * nf + 1], vbase + (size_t)jn * 16 + nf * 16384 + 512);
            }
        }
        // ---- counted wait: current buffer (+Q at it=0) done, next 16 in flight ----
        if (it < 3) asm volatile("s_waitcnt vmcnt(16)" ::: "memory");
        else        asm volatile("s_waitcnt vmcnt(0)"  ::: "memory");
        __builtin_amdgcn_sched_barrier(0);
        // ---- S^T tiles (row=key, col=query), exp, pack — per (nf, qs) ----
        unsigned pk01[2][4], pk23[2][4];
#pragma unroll
        for (int nf = 0; nf < 4; ++nf)
#pragma unroll
            for (int qs = 0; qs < 2; ++qs) {
                f32x4 z = {0.f, 0.f, 0.f, 0.f};
                z = __builtin_amdgcn_mfma_f32_16x16x32_bf16(kc[cur][2 * nf], qf[qs][0], z, 0, 0, 0);
                z = __builtin_amdgcn_mfma_f32_16x16x32_bf16(kc[cur][2 * nf + 1], qf[qs][1], z, 0, 0, 0);
                float p0 = __expf(z[0]);
                float p1 = __expf(z[1]);
                float p2 = __expf(z[2]);
                float p3 = __expf(z[3]);
                lp[qs] += (p0 + p1) + (p2 + p3);
                pk01[qs][nf] = pack2(p0, p1);
                pk23[qs][nf] = pack2(p2, p3);
            }
        // ---- register-only C->A transform (validated), per q-subtile ----
#pragma unroll
        for (int qs = 0; qs < 2; ++qs) {
            union PU { unsigned d[4]; bf16x8 v; } f0, f1;
            unsigned a0, a1;
            a0 = (unsigned)__builtin_amdgcn_ds_bpermute(sA,  (int)pk01[qs][0]);
            a1 = (unsigned)__builtin_amdgcn_ds_bpermute(sA,  (int)pk01[qs][1]);
            f0.d[0] = (quad < 2) ? a0 : a1;
            a0 = (unsigned)__builtin_amdgcn_ds_bpermute(sA,  (int)pk23[qs][0]);
            a1 = (unsigned)__builtin_amdgcn_ds_bpermute(sA,  (int)pk23[qs][1]);
            f0.d[1] = (quad < 2) ? a0 : a1;
            a0 = (unsigned)__builtin_amdgcn_ds_bpermute(sB2, (int)pk01[qs][0]);
            a1 = (unsigned)__builtin_amdgcn_ds_bpermute(sB2, (int)pk01[qs][1]);
            f0.d[2] = (quad < 2) ? a0 : a1;
            a0 = (unsigned)__builtin_amdgcn_ds_bpermute(sB2, (int)pk23[qs][0]);
            a1 = (unsigned)__builtin_amdgcn_ds_bpermute(sB2, (int)pk23[qs][1]);
            f0.d[3] = (quad < 2) ? a0 : a1;
            a0 = (unsigned)__builtin_amdgcn_ds_bpermute(sA,  (int)pk01[qs][2]);
            a1 = (unsigned)__builtin_amdgcn_ds_bpermute(sA,  (int)pk01[qs][3]);
            f1.d[0] = (quad < 2) ? a0 : a1;
            a0 = (unsigned)__builtin_amdgcn_ds_bpermute(sA,  (int)pk23[qs][2]);
            a1 = (unsigned)__builtin_amdgcn_ds_bpermute(sA,  (int)pk23[qs][3]);
            f1.d[1] = (quad < 2) ? a0 : a1;
            a0 = (unsigned)__builtin_amdgcn_ds_bpermute(sB2, (int)pk01[qs][2]);
            a1 = (unsigned)__builtin_amdgcn_ds_bpermute(sB2, (int)pk01[qs][3]);
            f1.d[2] = (quad < 2) ? a0 : a1;
            a0 = (unsigned)__builtin_amdgcn_ds_bpermute(sB2, (int)pk23[qs][2]);
            a1 = (unsigned)__builtin_amdgcn_ds_bpermute(sB2, (int)pk23[qs][3]);
            f1.d[3] = (quad < 2) ? a0 : a1;
            // ---- O += P.V ----
#pragma unroll
            for (int nf = 0; nf < 4; ++nf) {
                o[qs][nf] = __builtin_amdgcn_mfma_f32_16x16x32_bf16(f0.v, vf[cur][2 * nf], o[qs][nf], 0, 0, 0);
                o[qs][nf] = __builtin_amdgcn_mfma_f32_16x16x32_bf16(f1.v, vf[cur][2 * nf + 1], o[qs][nf], 0, 0, 0);
            }
        }
    }
    // ---- write per-wave partials to LDS ----
#pragma unroll
    for (int qs = 0; qs < 2; ++qs)
#pragma unroll
        for (int nf = 0; nf < 4; ++nf)
#pragma unroll
            for (int r = 0; r < 4; ++r)
                Ol[wave][qs * 16 + quad * 4 + r][nf * 16 + l16] = o[qs][nf][r];
#pragma unroll
    for (int qs = 0; qs < 2; ++qs) {
        float ts = lp[qs];
        ts += __shfl_xor(ts, 16, 64);
        ts += __shfl_xor(ts, 32, 64);
        if (quad == 0) Ls[wave][qs * 16 + l16] = ts;
    }
    __syncthreads();
    // ---- combine: wave w handles d-frag nf=w, 32 q rows ----
#pragma unroll
    for (int half = 0; half < 2; ++half)
#pragma unroll
        for (int r = 0; r < 4; ++r) {
            int qq = half * 16 + quad * 4 + r;
            float denom = Ls[0][qq] + Ls[1][qq] + Ls[2][qq] + Ls[3][qq];
            float v = Ol[0][qq][wave * 16 + l16] + Ol[1][qq][wave * 16 + l16]
                    + Ol[2][qq][wave * 16 + l16] + Ol[3][qq][wave * 16 + l16];
            int q = q0 + qq;
            av[((size_t)(b * 1024 + q)) * D + h * 64 + wave * 16 + l16] =
                f2bf(v / denom);
        }
}

// ---------------- classifier ----------------
__global__ __launch_bounds__(256) void cls_kernel(
    const float* __restrict__ x, const float* __restrict__ Wc,
    const float* __restrict__ bc, float* __restrict__ out)
{
    int lane = threadIdx.x & 63;
    int row = blockIdx.x * 4 + (threadIdx.x >> 6);
    const float* xr = x + (size_t)row * D + lane * 8;
    float4 v0 = *(const float4*)xr;
    float4 v1 = *(const float4*)(xr + 4);
    float acc[10];
#pragma unroll
    for (int c = 0; c < 10; ++c) {
        const float* wr = Wc + c * D + lane * 8;
        float4 w0 = *(const float4*)wr;
        float4 w1 = *(const float4*)(wr + 4);
        acc[c] = v0.x*w0.x + v0.y*w0.y + v0.z*w0.z + v0.w*w0.w
               + v1.x*w1.x + v1.y*w1.y + v1.z*w1.z + v1.w*w1.w;
    }
#pragma unroll
    for (int c = 0; c < 10; ++c)
#pragma unroll
        for (int off = 32; off; off >>= 1) acc[c] += __shfl_xor(acc[c], off, 64);
    if (lane == 0) {
#pragma unroll
        for (int c = 0; c < 10; ++c) out[(size_t)row * 10 + c] = acc[c] + bc[c];
    }
}

extern "C" void kernel_launch(void* const* d_in, const int* in_sizes, int n_in,
                              void* d_out, int out_size, void* d_ws, size_t ws_size,
                              hipStream_t stream)
{
    const int*   tokens = (const int*)  d_in[0];
    const float* emb    = (const float*)d_in[1];
    const float* Wq     = (const float*)d_in[2];
    const float* bq     = (const float*)d_in[3];
    const float* Wkv    = (const float*)d_in[4];
    const float* bkv    = (const float*)d_in[5];
    const float* Wo     = (const float*)d_in[6];
    const float* bo     = (const float*)d_in[7];
    const float* ln1g   = (const float*)d_in[8];
    const float* ln1b   = (const float*)d_in[9];
    const float* W1     = (const float*)d_in[10];
    const float* b1     = (const float*)d_in[11];
    const float* W2     = (const float*)d_in[12];
    const float* b2     = (const float*)d_in[13];
    const float* ln2g   = (const float*)d_in[14];
    const float* ln2b   = (const float*)d_in[15];
    const float* Wc     = (const float*)d_in[16];
    const float* bc     = (const float*)d_in[17];
    float* out = (float*)d_out;

    // workspace (~64 MB; harness poisons >=268MB per fillBuffer WRITE_SIZE):
    // x fp32 8MB | hb bf16 4MB | Qb 4 | Kb 4 | Vt 4 | avb 4 (f1b aliases Qb..)
    // | wl bf16 6x6MB = 36MB | wbias fp32 36KB
    float* x  = (float*)d_ws;
    unsigned short* hb  = (unsigned short*)(x + (size_t)MTOK * D);
    unsigned short* Qb  = hb  + (size_t)MTOK * D;
    unsigned short* Kb  = Qb  + (size_t)32 * 1024 * 64;
    unsigned short* Vt  = Kb  + (size_t)32 * 1024 * 64;
    unsigned short* avb = Vt  + (size_t)32 * 1024 * 64;
    unsigned short* f1b = Qb;                              // [4096][2048] bf16 = 16 MB
    unsigned short* wl  = avb + (size_t)32 * 1024 * 64;    // all-layer bf16 weights (36 MB)
    float* wbias = (float*)(wl + (size_t)6 * 3145728);     // combined [bq;bkv] x 6 (36 KB)

    // per-layer wl layout: [Wq;Wkv] contiguous 1536x512, then Wo, W1, W2
    const size_t oWo = 786432, oW1 = 1048576, oW2 = 2097152, LW = 3145728;

    prep_kernel<<<11265, 256, 0, stream>>>(
        tokens, emb, Wq, Wkv, Wo, W1, W2, bq, bkv, wl, wbias, x);

    for (int l = 0; l < NLAYER; ++l) {
        const unsigned short* wll = wl + (size_t)l * LW;
        ln_kernel<<<MTOK / 4, 256, 0, stream>>>(x, ln1g + l * D, ln1b + l * D, hb);
        gemm_bf16<2,128,64,64><<<dim3(24, 32), 256, 0, stream>>>(
            hb, wll, wbias + l * 1536, nullptr, Qb, Kb, Vt, MTOK, 1536, 512);
        attn_mfma<<<1024, 256, 0, stream>>>(Qb, Kb, Vt, avb);
        gemm_bf16<0,64,64,128><<<dim3(8, 64), 256, 0, stream>>>(
            avb, wll + oWo, bo + l * D, x, x, nullptr, nullptr, MTOK, D, D);
        ln_kernel<<<MTOK / 4, 256, 0, stream>>>(x, ln2g + l * D, ln2b + l * D, hb);
        gemm_bf16<1,128,128,64><<<dim3(16, 32), 256, 0, stream>>>(
            hb, wll + oW1, b1 + l * 4 * D, nullptr, f1b, nullptr, nullptr, MTOK, 4 * D, D);
        gemm_bf16<0,64,64,128><<<dim3(8, 64), 256, 0, stream>>>(
            f1b, wll + oW2, b2 + l * D, x, x, nullptr, nullptr, MTOK, D, 4 * D);
    }

    cls_kernel<<<MTOK / 4, 256, 0, stream>>>(x, Wc, bc, out);
}